// Round 11
// baseline (430.790 us; speedup 1.0000x reference)
//
#include <hip/hip_runtime.h>
#include <math.h>

#define NB 32              // batches per block
#define KC 4               // k-rows staged per chunk
#define NCH 32             // 128/KC chunks
#define RST 36             // staged stride per orbital r (32 data + 4 pad floats)
#define SKK 2304           // staged floats per k-row: 64 orbitals * RST
#define STAGE_FLOATS (KC*SKK)      // 9216 floats = 36 KB
#define ROWSTRIDE 20
#define MATSTRIDE 644
#define AMAT_FLOATS (16*MATSTRIDE) // 10304 floats = 41.2 KB (16-batch LU round)
#define ARENA_FLOATS (AMAT_FLOATS) // max(stage, amat)

// R7-R10: four MLP/occupancy variants all pin at ~285us => hard per-CU L2->CU
// line rate (~2.6 cy per 64B line, 15.2 TB/s aggregate). Only fix: move fewer
// lines. W is 1 MB; staging each k-chunk once per 32-batch block halves the
// per-CU line traffic (131072 vs 262144 lines/CU). Staged layout is
// bank-swizzled (stride 36/orbital) because W's natural layout puts all gather
// reads in 8 bank-quads. A-rows accumulate in registers (k-ascending order =>
// arithmetic identical to R7-R10); LU (R9 code) runs in two 16-batch rounds
// reusing the stage arena.
// output: planar complex: out[b] = re, out[B+b] = im (verified R6).

__global__ __launch_bounds__(256, 3) void backflow_kernel(
    const int* __restrict__ nocc,   // (B,128) int32 0/1
    const float* __restrict__ W,    // (128,2048) f32 row-major
    float* __restrict__ out,        // planar: [B re][B im]
    int B)
{
    __shared__ int lists[NB][33];
    __shared__ float arena[ARENA_FLOATS];   // stage (36KB) then amat (41.2KB)

    const int tid = threadIdx.x;

    // ---------------- phase 1: occupancy -> sorted k lists (8 lanes/batch) ----------------
    {
        const int bib1 = tid >> 3;                 // 0..31
        const int l8   = tid & 7;                  // lanes 0-3: up half, 4-7: dn half
        int batch1 = blockIdx.x * NB + bib1;
        if (batch1 >= B) batch1 = B - 1;
        const int4* np = reinterpret_cast<const int4*>(nocc + (size_t)batch1 * 128 + l8 * 16);
        int4 v0 = np[0], v1 = np[1], v2 = np[2], v3 = np[3];
        unsigned nib = 0;
        nib |= (v0.x != 0) ? (1u<<0)  : 0u;  nib |= (v0.y != 0) ? (1u<<1)  : 0u;
        nib |= (v0.z != 0) ? (1u<<2)  : 0u;  nib |= (v0.w != 0) ? (1u<<3)  : 0u;
        nib |= (v1.x != 0) ? (1u<<4)  : 0u;  nib |= (v1.y != 0) ? (1u<<5)  : 0u;
        nib |= (v1.z != 0) ? (1u<<6)  : 0u;  nib |= (v1.w != 0) ? (1u<<7)  : 0u;
        nib |= (v2.x != 0) ? (1u<<8)  : 0u;  nib |= (v2.y != 0) ? (1u<<9)  : 0u;
        nib |= (v2.z != 0) ? (1u<<10) : 0u;  nib |= (v2.w != 0) ? (1u<<11) : 0u;
        nib |= (v3.x != 0) ? (1u<<12) : 0u;  nib |= (v3.y != 0) ? (1u<<13) : 0u;
        nib |= (v3.z != 0) ? (1u<<14) : 0u;  nib |= (v3.w != 0) ? (1u<<15) : 0u;
        const int cnt = __popc(nib);
        int incl = cnt;
        const int seg = l8 & 3;                    // 4-lane segment within spin half
        #pragma unroll
        for (int d = 1; d < 4; d <<= 1) {
            int t = __shfl_up(incl, d, 4);
            if (seg >= d) incl += t;
        }
        int pos = ((l8 >> 2) << 4) + (incl - cnt); // spin*16 + exclusive prefix
        const int k0 = l8 * 16;
        #pragma unroll
        for (int b = 0; b < 16; b++) {
            if (nib & (1u << b)) lists[bib1][pos++] = k0 + b;
        }
    }
    __syncthreads();

    // ---------------- phase 2: chunked LDS staging + register gather ----------------
    const int wv = tid >> 6;
    const int ln = tid & 63;
    const int ridx = ln >> 2;        // lane's row index within a spin (0..15)
    const int q    = ln & 3;         // lane's quarter (4 floats)

    // per-batch invariants for this wave's 8 batches
    int base0[8], base1[8], ptr[8];
    float4 acc0[8], acc1[8];
    #pragma unroll
    for (int bb = 0; bb < 8; bb++) {
        const int b = wv * 8 + bb;
        const int r0 = lists[b][ridx];            // up orbital in [0,64)
        const int r1 = lists[b][16 + ridx] - 64;  // dn orbital in [0,64)
        base0[bb] = r0 * RST + q * 4;             // m=0 half
        base1[bb] = r1 * RST + 16 + q * 4;        // m=1 half
        ptr[bb] = 0;
        acc0[bb] = make_float4(0.f, 0.f, 0.f, 0.f);
        acc1[bb] = make_float4(0.f, 0.f, 0.f, 0.f);
    }

    const float4* Wv4 = reinterpret_cast<const float4*>(W);

    #pragma unroll 1
    for (int ch = 0; ch < NCH; ch++) {
        __syncthreads();   // previous gather reads done before restaging
        {
            float4 w8[8];
            #pragma unroll
            for (int i = 0; i < 8; i++) {
                const int p = i * 256 + tid;       // float4 index in chunk [0,2048)
                const int kk = p >> 9, c4 = p & 511;
                w8[i] = Wv4[(size_t)(ch * KC + kk) * 512 + c4];
            }
            #pragma unroll
            for (int i = 0; i < 8; i++) {
                const int p = i * 256 + tid;
                const int kk = p >> 9, c4 = p & 511;
                const int r = c4 >> 3, m = (c4 >> 2) & 1, qq = c4 & 3;
                *reinterpret_cast<float4*>(&arena[kk * SKK + r * RST + m * 16 + qq * 4]) = w8[i];
            }
        }
        __syncthreads();

        const int kend = (ch + 1) * KC;
        #pragma unroll
        for (int bb = 0; bb < 8; bb++) {
            const int b = wv * 8 + bb;
            int p = ptr[bb];
            while (p < 32) {                       // wave-uniform walk of sorted k-list
                const int k = lists[b][p];
                if (k >= kend) break;
                const int off = (k - ch * KC) * SKK;
                const float4 u = *reinterpret_cast<const float4*>(&arena[off + base0[bb]]);
                const float4 v = *reinterpret_cast<const float4*>(&arena[off + base1[bb]]);
                acc0[bb].x += u.x; acc0[bb].y += u.y; acc0[bb].z += u.z; acc0[bb].w += u.w;
                acc1[bb].x += v.x; acc1[bb].y += v.y; acc1[bb].z += v.z; acc1[bb].w += v.w;
                p++;
            }
            ptr[bb] = p;
        }
    }

    // ---------------- phase 3: two 16-batch LU rounds (arena reused as amat) ----------------
    #pragma unroll 1
    for (int h = 0; h < 2; h++) {
        __syncthreads();   // arena free (stage reads done / previous LU done)
        if ((wv >> 1) == h) {
            #pragma unroll
            for (int bb = 0; bb < 8; bb++) {
                const int lb = wv * 8 + bb;        // in [h*16, h*16+16)
                const int bloc = lb & 15;
                *reinterpret_cast<float4*>(&arena[bloc * MATSTRIDE + ridx * ROWSTRIDE + q * 4]) = acc0[bb];
                *reinterpret_cast<float4*>(&arena[bloc * MATSTRIDE + (16 + ridx) * ROWSTRIDE + q * 4]) = acc1[bb];
            }
        }
        __syncthreads();

        const int gg   = wv * 8 + (ln >> 3);       // matrix 0..31 (16 batches x 2 spins)
        const int s8   = ln & 7;
        const int bloc = gg >> 1;
        const int m    = gg & 1;
        int batch = blockIdx.x * NB + h * 16 + bloc;
        const bool valid = (batch < B);
        if (batch >= B) batch = B - 1;

        float a0[16], a1[16];
        {
            const float* row0 = &arena[bloc * MATSTRIDE + (m * 16 + s8) * ROWSTRIDE];
            const float* row1 = row0 + 8 * ROWSTRIDE;
            #pragma unroll
            for (int qq = 0; qq < 4; qq++) {
                float4 v0 = *reinterpret_cast<const float4*>(row0 + qq * 4);
                float4 v1 = *reinterpret_cast<const float4*>(row1 + qq * 4);
                a0[qq*4+0] = v0.x; a0[qq*4+1] = v0.y; a0[qq*4+2] = v0.z; a0[qq*4+3] = v0.w;
                a1[qq*4+0] = v1.x; a1[qq*4+1] = v1.y; a1[qq*4+2] = v1.z; a1[qq*4+3] = v1.w;
            }
        }

        unsigned active = 0xffffu;
        int inv = 0;
        float myd0 = 1.f, myd1 = 1.f;

        #pragma unroll
        for (int k = 0; k < 16; k++) {
            const unsigned act0 = (active >> s8) & 1u;
            const unsigned act1 = (active >> (s8 + 8)) & 1u;
            float av = act0 ? fabsf(a0[k]) : -1.f;
            int idx = s8;
            {
                float av1 = act1 ? fabsf(a1[k]) : -1.f;
                if (av1 > av) { av = av1; idx = s8 + 8; }
            }
            #pragma unroll
            for (int d = 1; d < 8; d <<= 1) {
                float ov = __shfl_xor(av, d, 8);
                int   oi = __shfl_xor(idx, d, 8);
                if (ov > av || (ov == av && oi < idx)) { av = ov; idx = oi; }
            }
            const int p = idx;
            const int plane = p & 7;
            const bool phi = (p & 8) != 0;
            float psel = phi ? a1[k] : a0[k];
            const float pk = __shfl(psel, plane, 8);
            const float rcp = 1.0f / pk;

            if (s8 == p)     myd0 = pk;
            if (s8 + 8 == p) myd1 = pk;
            inv += __popc(active & ((1u << p) - 1u));
            active &= ~(1u << p);

            const float f0 = (act0 && s8 != p)       ? a0[k] * rcp : 0.f;
            const float f1 = (act1 && (s8 + 8) != p) ? a1[k] * rcp : 0.f;

            #pragma unroll
            for (int j = k + 1; j < 16; j++) {
                float sel = phi ? a1[j] : a0[j];
                float pv = __shfl(sel, plane, 8);
                a0[j] = fmaf(-f0, pv, a0[j]);
                a1[j] = fmaf(-f1, pv, a1[j]);
            }
        }

        float ld = logf(fabsf(myd0)) + logf(fabsf(myd1));
        int ng = ((myd0 < 0.f) ? 1 : 0) + ((myd1 < 0.f) ? 1 : 0);
        #pragma unroll
        for (int d = 1; d < 8; d <<= 1) {
            ld += __shfl_xor(ld, d, 8);
            ng += __shfl_xor(ng, d, 8);
        }
        const int neg = (ng + inv) & 1;

        const float ld_o  = __shfl_xor(ld, 8, 16);
        const int   neg_o = __shfl_xor(neg, 8, 16);

        if ((ln & 15) == 0 && valid) {
            out[batch]     = ld + ld_o;                                      // re plane
            out[B + batch] = 3.14159265358979323846f * (float)(neg + neg_o); // im plane
        }
    }
}

extern "C" void kernel_launch(void* const* d_in, const int* in_sizes, int n_in,
                              void* d_out, int out_size, void* d_ws, size_t ws_size,
                              hipStream_t stream) {
    const int* nocc = (const int*)d_in[0];
    const float* W  = (const float*)d_in[1];
    float* out = (float*)d_out;
    const int B = in_sizes[0] / 128;                 // 65536
    const int blocks = (B + NB - 1) / NB;            // 2048
    backflow_kernel<<<blocks, 256, 0, stream>>>(nocc, W, out, B);
}